// Round 1
// baseline (755.385 us; speedup 1.0000x reference)
//
#include <hip/hip_runtime.h>
#include <hip/hip_bf16.h>

#define SEQ 2048
#define DM 2048
#define NH 16
#define DK 128
#define LOG2E 1.4426950408889634f
#define QK_SCALE 0.08838834764831845f   // 128^-0.5

typedef __attribute__((ext_vector_type(8))) short short8;
typedef __attribute__((ext_vector_type(4))) float f32x4;
typedef __attribute__((ext_vector_type(4))) unsigned short us4;

__device__ __forceinline__ unsigned short f2b(float f) {
  union { float f; unsigned u; } v; v.f = f;
  unsigned r = v.u + 0x7fffu + ((v.u >> 16) & 1u);
  return (unsigned short)(r >> 16);
}

__device__ __forceinline__ void gl_lds16(const void* g, void* l) {
  __builtin_amdgcn_global_load_lds((const __attribute__((address_space(1))) void*)g,
                                   (__attribute__((address_space(3))) void*)l, 16, 0, 0);
}

// ---------------- cast states f32 -> bf16 ----------------
__global__ __launch_bounds__(256) void cast_bf16_kernel(const float* __restrict__ in,
                                                        unsigned short* __restrict__ out) {
  int i = blockIdx.x * 256 + threadIdx.x;   // 8 floats per thread, grid sized exactly
  const float4* p = (const float4*)in;
  float4 a = p[2*i], b = p[2*i+1];
  us4 r0, r1;
  r0[0]=f2b(a.x); r0[1]=f2b(a.y); r0[2]=f2b(a.z); r0[3]=f2b(a.w);
  r1[0]=f2b(b.x); r1[1]=f2b(b.y); r1[2]=f2b(b.z); r1[3]=f2b(b.w);
  us4* o = (us4*)out;
  o[2*i] = r0; o[2*i+1] = r1;
}

// ---------------- transpose + cast: w[2048][2048] f32 -> wt[2048][2048] bf16 (wt = w^T) ----
__global__ __launch_bounds__(256) void transpose_cast_kernel(const float* __restrict__ w,
                                                             unsigned short* __restrict__ wt) {
  __shared__ float t[64][65];
  int c0 = blockIdx.x * 64, r0 = blockIdx.y * 64;
  int tid = threadIdx.x;
  int rr = tid >> 4;           // 0..15
  int c4 = (tid & 15) * 4;     // 0..60
#pragma unroll
  for (int p = 0; p < 4; ++p) {
    int r = p*16 + rr;
    float4 v = *(const float4*)&w[(size_t)(r0 + r)*DM + c0 + c4];
    t[r][c4] = v.x; t[r][c4+1] = v.y; t[r][c4+2] = v.z; t[r][c4+3] = v.w;
  }
  __syncthreads();
#pragma unroll
  for (int p = 0; p < 4; ++p) {
    int c = p*16 + rr;         // column of w = row of wt
    us4 v;
    v[0] = f2b(t[c4+0][c]); v[1] = f2b(t[c4+1][c]);
    v[2] = f2b(t[c4+2][c]); v[3] = f2b(t[c4+3][c]);
    *(us4*)&wt[(size_t)(c0 + c)*DM + r0 + c4] = v;
  }
}

// ---------------- GEMM: C[m][n] = sum_k A[m][k]*Bt[n][k] (+bias), m97 structure ----------
// M=4096, N=2048, K=2048. MODE: 0 = f32 out row-major; 1 = Q bf16 [b,h,s,d] *QK_SCALE*LOG2E;
// 2 = K bf16 [b,h,s,d]; 3 = V^T bf16 [b,h,d,s].
template<int MODE>
__global__ __launch_bounds__(256) void gemm_bt_kernel(const unsigned short* __restrict__ A,
                                                      const unsigned short* __restrict__ Bt,
                                                      const float* __restrict__ bias,
                                                      void* __restrict__ outp) {
  __shared__ __align__(16) unsigned short As[128*32];
  __shared__ __align__(16) unsigned short Bs[128*32];
  const int K = DM;
  int bid = blockIdx.x;
  int tm = bid >> 4, tn = bid & 15;
  int m0 = tm*128, n0 = tn*128;
  int tid = threadIdx.x;
  int wid = tid >> 6, lane = tid & 63;
  int lo = lane & 15, hi = lane >> 4;
  int wm = (wid >> 1) * 64, wn = (wid & 1) * 64;

  f32x4 z = {0.f,0.f,0.f,0.f};
  f32x4 acc[4][4];
#pragma unroll
  for (int i = 0; i < 4; ++i)
#pragma unroll
    for (int j = 0; j < 4; ++j) acc[i][j] = z;

  int srow = lane >> 2;        // 0..15
  int sko  = (lane & 3) * 8;   // bf16-element offset (16B chunks)

  for (int kt = 0; kt < K; kt += 32) {
#pragma unroll
    for (int i = 0; i < 2; ++i) {
      int row = (wid*2 + i)*16 + srow;
      gl_lds16(&A [(size_t)(m0 + row)*K + kt + sko], &As[(wid*2 + i)*512]);
      gl_lds16(&Bt[(size_t)(n0 + row)*K + kt + sko], &Bs[(wid*2 + i)*512]);
    }
    __syncthreads();
    short8 af[4], bf[4];
#pragma unroll
    for (int f = 0; f < 4; ++f) {
      af[f] = *(const short8*)&As[(wm + f*16 + lo)*32 + hi*8];
      bf[f] = *(const short8*)&Bs[(wn + f*16 + lo)*32 + hi*8];
    }
#pragma unroll
    for (int mf = 0; mf < 4; ++mf)
#pragma unroll
      for (int nf = 0; nf < 4; ++nf)
        acc[mf][nf] = __builtin_amdgcn_mfma_f32_16x16x32_bf16(af[mf], bf[nf], acc[mf][nf], 0, 0, 0);
    __syncthreads();
  }

  if (MODE == 0) {
    float* out = (float*)outp;
#pragma unroll
    for (int mf = 0; mf < 4; ++mf)
#pragma unroll
      for (int nf = 0; nf < 4; ++nf) {
        int n = n0 + wn + nf*16 + lo;
        float bv = bias[n];
#pragma unroll
        for (int r = 0; r < 4; ++r) {
          int m = m0 + wm + mf*16 + 4*hi + r;
          out[(size_t)m*DM + n] = acc[mf][nf][r] + bv;
        }
      }
  } else if (MODE == 3) {
    unsigned short* out = (unsigned short*)outp;
#pragma unroll
    for (int mf = 0; mf < 4; ++mf) {
      int mb = m0 + wm + mf*16 + 4*hi;
      int b = mb >> 11, s = mb & 2047;
#pragma unroll
      for (int nf = 0; nf < 4; ++nf) {
        int n = n0 + wn + nf*16 + lo;
        int h = n >> 7, d = n & 127;
        float bv = bias[n];
        us4 pk;
#pragma unroll
        for (int r = 0; r < 4; ++r) pk[r] = f2b(acc[mf][nf][r] + bv);
        *(us4*)&out[(((size_t)(b*NH + h))*DK + d)*SEQ + s] = pk;
      }
    }
  } else {
    unsigned short* out = (unsigned short*)outp;
    const float qs = QK_SCALE * LOG2E;
#pragma unroll
    for (int mf = 0; mf < 4; ++mf)
#pragma unroll
      for (int nf = 0; nf < 4; ++nf) {
        int n = n0 + wn + nf*16 + lo;
        int h = n >> 7, d = n & 127;
        float bv = bias[n];
#pragma unroll
        for (int r = 0; r < 4; ++r) {
          int m = m0 + wm + mf*16 + 4*hi + r;
          int b = m >> 11, s = m & 2047;
          float v = acc[mf][nf][r] + bv;
          if (MODE == 1) v *= qs;
          out[(((size_t)(b*NH + h))*SEQ + s)*DK + d] = f2b(v);
        }
      }
  }
}

// ---------------- gate: G[row][h] = sigmoid(X[row]·wg[:,h] + bg[h]) ----------------
__global__ __launch_bounds__(256) void gate_kernel(const float* __restrict__ X,
                                                   const float* __restrict__ wg,
                                                   const float* __restrict__ bg,
                                                   float* __restrict__ G) {
  __shared__ float xr[DM];
  int row = blockIdx.x;
  int tid = threadIdx.x;
  const float4* src = (const float4*)(X + (size_t)row*DM);
#pragma unroll
  for (int i = 0; i < 2; ++i)
    ((float4*)xr)[tid + i*256] = src[tid + i*256];
  __syncthreads();
  int wid = tid >> 6, lane = tid & 63;
#pragma unroll
  for (int hh = 0; hh < 4; ++hh) {
    int h = wid*4 + hh;
    float s = 0.f;
    for (int i = lane; i < DM; i += 64)
      s += xr[i] * wg[(size_t)i*NH + h];
#pragma unroll
    for (int m = 32; m >= 1; m >>= 1) s += __shfl_xor(s, m);
    if (lane == 0) {
      float x = s + bg[h];
      G[(size_t)row*NH + h] = 1.f / (1.f + __builtin_amdgcn_exp2f(-x * LOG2E));
    }
  }
}

// ---------------- flash attention ----------------
// Q [bh][s][d] bf16 (pre-scaled by QK_SCALE*LOG2E), K [bh][s][d] bf16, VT [bh][d][s] bf16.
// grid: (qt, b, h) with h fastest for bias L2 reuse. 4 waves x 16 q-rows, KT=64.
__global__ __launch_bounds__(256) void attn_kernel(const unsigned short* __restrict__ Q,
                                                   const unsigned short* __restrict__ Kb,
                                                   const unsigned short* __restrict__ VT,
                                                   const float* __restrict__ bias_mask,
                                                   const float* __restrict__ G,
                                                   unsigned short* __restrict__ OG) {
  __shared__ __align__(16) unsigned short kbuf[64*128];  // [key][d], xor-swizzled rows (256B)
  __shared__ __align__(16) unsigned short vbuf[128*64];  // [d][key], xor-swizzled rows (128B)
  __shared__ __align__(16) float pbuf[4][16*68];         // per-wave P, padded stride 68

  int bid = blockIdx.x;
  int h  = bid & 15;
  int b  = (bid >> 4) & 1;
  int qt = bid >> 5;
  int bh = b*NH + h;
  int q0 = qt*64;

  int tid = threadIdx.x, wid = tid >> 6, lane = tid & 63;
  int lo = lane & 15, hi = lane >> 4;
  int qw0 = q0 + wid*16;

  float hs2 = __builtin_amdgcn_exp2f(-(float)(h+1) * 0.5f) * LOG2E;

  short8 qf[4];
#pragma unroll
  for (int ks = 0; ks < 4; ++ks)
    qf[ks] = *(const short8*)&Q[((size_t)bh*SEQ + qw0 + lo)*DK + ks*32 + hi*8];

  f32x4 zero4 = {0.f,0.f,0.f,0.f};
  f32x4 acco[8];
#pragma unroll
  for (int f = 0; f < 8; ++f) acco[f] = zero4;
  float mrun[4], lrun[4];
#pragma unroll
  for (int r = 0; r < 4; ++r) { mrun[r] = -__builtin_inff(); lrun[r] = 0.f; }

  const char* kbase = (const char*)Kb + ((size_t)bh*SEQ)*DK*2;
  const char* vbase = (const char*)VT + ((size_t)bh*DK)*SEQ*2;

  for (int kt = 0; kt < SEQ; kt += 64) {
    // ---- stage K tile [64][128] and V^T tile [128][64] with pre-swizzled global source ----
#pragma unroll
    for (int i = 0; i < 4; ++i) {
      int lin = (wid*4 + i)*1024 + lane*16;
      int row = lin >> 8, off = lin & 255;
      int soff = off ^ ((row & 7) << 4);
      gl_lds16(kbase + (size_t)(kt + row)*256 + soff, (char*)kbuf + (size_t)(wid*4 + i)*1024);
      int rowv = lin >> 7, offv = lin & 127;
      int soffv = offv ^ ((rowv & 7) << 4);
      gl_lds16(vbase + (size_t)rowv*(SEQ*2) + kt*2 + soffv, (char*)vbuf + (size_t)(wid*4 + i)*1024);
    }
    __syncthreads();

    // ---- QK^T: S[16q x 64k] per wave ----
    f32x4 sf[4];
#pragma unroll
    for (int nf = 0; nf < 4; ++nf) {
      f32x4 a = zero4;
#pragma unroll
      for (int ks = 0; ks < 4; ++ks) {
        int krow = nf*16 + lo;
        int cb = (ks*32 + hi*8)*2;
        short8 kf = *(const short8*)((const char*)kbuf + krow*256 + (cb ^ ((krow & 7) << 4)));
        a = __builtin_amdgcn_mfma_f32_16x16x32_bf16(qf[ks], kf, a, 0, 0, 0);
      }
      sf[nf] = a;
    }
    // ---- add alibi-scaled bias (already includes LOG2E fold via hs2) ----
#pragma unroll
    for (int nf = 0; nf < 4; ++nf)
#pragma unroll
      for (int r = 0; r < 4; ++r) {
        int qrow = qw0 + 4*hi + r;
        int key = kt + nf*16 + lo;
        sf[nf][r] += bias_mask[((size_t)b*SEQ + qrow)*SEQ + key] * hs2;
      }
    // ---- online softmax (base 2) ----
    float sc[4];
#pragma unroll
    for (int r = 0; r < 4; ++r) {
      float tm = fmaxf(fmaxf(sf[0][r], sf[1][r]), fmaxf(sf[2][r], sf[3][r]));
      tm = fmaxf(tm, __shfl_xor(tm, 1));
      tm = fmaxf(tm, __shfl_xor(tm, 2));
      tm = fmaxf(tm, __shfl_xor(tm, 4));
      tm = fmaxf(tm, __shfl_xor(tm, 8));
      float mnew = fmaxf(mrun[r], tm);
      float s = __builtin_amdgcn_exp2f(mrun[r] - mnew);
      mrun[r] = mnew; sc[r] = s;
      float rs = 0.f;
#pragma unroll
      for (int nf = 0; nf < 4; ++nf) {
        float p = __builtin_amdgcn_exp2f(sf[nf][r] - mnew);
        rs += p;
        pbuf[wid][(4*hi + r)*68 + nf*16 + lo] = p;
      }
      rs += __shfl_xor(rs, 1); rs += __shfl_xor(rs, 2);
      rs += __shfl_xor(rs, 4); rs += __shfl_xor(rs, 8);
      lrun[r] = lrun[r]*s + rs;
    }
#pragma unroll
    for (int f = 0; f < 8; ++f)
#pragma unroll
      for (int r = 0; r < 4; ++r) acco[f][r] *= sc[r];

    // ---- PV: O[16q x 128d] += P[16q x 64k] * V[64k x 128d] ----
    short8 pf[2];
#pragma unroll
    for (int ks = 0; ks < 2; ++ks) {
      f32x4 pa = *(const f32x4*)&pbuf[wid][lo*68 + ks*32 + hi*8];
      f32x4 pb = *(const f32x4*)&pbuf[wid][lo*68 + ks*32 + hi*8 + 4];
      short8 t;
      t[0]=(short)f2b(pa[0]); t[1]=(short)f2b(pa[1]); t[2]=(short)f2b(pa[2]); t[3]=(short)f2b(pa[3]);
      t[4]=(short)f2b(pb[0]); t[5]=(short)f2b(pb[1]); t[6]=(short)f2b(pb[2]); t[7]=(short)f2b(pb[3]);
      pf[ks] = t;
    }
#pragma unroll
    for (int f = 0; f < 8; ++f) {
#pragma unroll
      for (int ks = 0; ks < 2; ++ks) {
        int vrow = f*16 + lo;
        int cb = (ks*32 + hi*8)*2;
        short8 vf = *(const short8*)((const char*)vbuf + vrow*128 + (cb ^ ((vrow & 7) << 4)));
        acco[f] = __builtin_amdgcn_mfma_f32_16x16x32_bf16(pf[ks], vf, acco[f], 0, 0, 0);
      }
    }
    __syncthreads();
  }

  // ---- epilogue: normalize, gate, write OG[b,s, h*128+d] bf16 ----
#pragma unroll
  for (int r = 0; r < 4; ++r) {
    int qrow = qw0 + 4*hi + r;
    float inv = 1.f / lrun[r];
    float g = G[((size_t)(b*SEQ + qrow))*NH + h];
    float sgl = inv * g;
#pragma unroll
    for (int f = 0; f < 8; ++f)
      OG[((size_t)(b*SEQ) + qrow)*DM + h*DK + f*16 + lo] = f2b(acco[f][r] * sgl);
  }
}

// ---------------- launcher ----------------
extern "C" void kernel_launch(void* const* d_in, const int* in_sizes, int n_in,
                              void* d_out, int out_size, void* d_ws, size_t ws_size,
                              hipStream_t stream) {
  const float* states    = (const float*)d_in[0];
  const float* bias_mask = (const float*)d_in[1];
  const float* wq = (const float*)d_in[2];
  const float* bq = (const float*)d_in[3];
  const float* wk = (const float*)d_in[4];
  const float* bk = (const float*)d_in[5];
  const float* wv = (const float*)d_in[6];
  const float* bv = (const float*)d_in[7];
  const float* wg = (const float*)d_in[8];
  const float* bg = (const float*)d_in[9];
  const float* wo = (const float*)d_in[10];
  const float* bo = (const float*)d_in[11];

  char* ws = (char*)d_ws;
  unsigned short* XB  = (unsigned short*)(ws + 0);
  unsigned short* WQT = (unsigned short*)(ws + 16777216UL);
  unsigned short* WKT = (unsigned short*)(ws + 25165824UL);
  unsigned short* WVT = (unsigned short*)(ws + 33554432UL);
  unsigned short* WOT = (unsigned short*)(ws + 41943040UL);
  unsigned short* QB  = (unsigned short*)(ws + 50331648UL);
  unsigned short* KB  = (unsigned short*)(ws + 67108864UL);
  unsigned short* VTB = (unsigned short*)(ws + 83886080UL);
  unsigned short* OGB = (unsigned short*)(ws + 100663296UL);
  float*          GB  = (float*)         (ws + 117440512UL);

  cast_bf16_kernel<<<4096, 256, 0, stream>>>(states, XB);
  dim3 tg(32, 32);
  transpose_cast_kernel<<<tg, 256, 0, stream>>>(wq, WQT);
  transpose_cast_kernel<<<tg, 256, 0, stream>>>(wk, WKT);
  transpose_cast_kernel<<<tg, 256, 0, stream>>>(wv, WVT);
  transpose_cast_kernel<<<tg, 256, 0, stream>>>(wo, WOT);

  gemm_bt_kernel<1><<<512, 256, 0, stream>>>(XB, WQT, bq, QB);
  gemm_bt_kernel<2><<<512, 256, 0, stream>>>(XB, WKT, bk, KB);
  gemm_bt_kernel<3><<<512, 256, 0, stream>>>(XB, WVT, bv, VTB);

  gate_kernel<<<4096, 256, 0, stream>>>(states, wg, bg, GB);

  attn_kernel<<<1024, 256, 0, stream>>>(QB, KB, VTB, bias_mask, GB, OGB);

  gemm_bt_kernel<0><<<512, 256, 0, stream>>>(OGB, WOT, bo, d_out);
}

// Round 2
// 713.386 us; speedup vs baseline: 1.0589x; 1.0589x over previous
//
#include <hip/hip_runtime.h>
#include <hip/hip_bf16.h>

#define SEQ 2048
#define DM 2048
#define NH 16
#define DK 128
#define LOG2E 1.4426950408889634f
#define QK_SCALE 0.08838834764831845f   // 128^-0.5

typedef __attribute__((ext_vector_type(8))) short short8;
typedef __attribute__((ext_vector_type(4))) float f32x4;
typedef __attribute__((ext_vector_type(4))) unsigned short us4;

__device__ __forceinline__ unsigned short f2b(float f) {
  union { float f; unsigned u; } v; v.f = f;
  unsigned r = v.u + 0x7fffu + ((v.u >> 16) & 1u);
  return (unsigned short)(r >> 16);
}
__device__ __forceinline__ float b2f(unsigned short v) {
  union { unsigned u; float f; } x; x.u = ((unsigned)v) << 16; return x.f;
}

__device__ __forceinline__ void gl_lds16(const void* g, void* l) {
  __builtin_amdgcn_global_load_lds((const __attribute__((address_space(1))) void*)g,
                                   (__attribute__((address_space(3))) void*)l, 16, 0, 0);
}

// ---------------- cast f32 -> bf16 (8 elems/thread, grid sized exactly) ----------------
__global__ __launch_bounds__(256) void cast_bf16_kernel(const float* __restrict__ in,
                                                        unsigned short* __restrict__ out) {
  int i = blockIdx.x * 256 + threadIdx.x;
  const float4* p = (const float4*)in;
  float4 a = p[2*i], b = p[2*i+1];
  us4 r0, r1;
  r0[0]=f2b(a.x); r0[1]=f2b(a.y); r0[2]=f2b(a.z); r0[3]=f2b(a.w);
  r1[0]=f2b(b.x); r1[1]=f2b(b.y); r1[2]=f2b(b.z); r1[3]=f2b(b.w);
  us4* o = (us4*)out;
  o[2*i] = r0; o[2*i+1] = r1;
}

// ---------------- transpose + cast: w[2048][2048] f32 -> wt = w^T bf16 ----------------
__global__ __launch_bounds__(256) void transpose_cast_kernel(const float* __restrict__ w,
                                                             unsigned short* __restrict__ wt) {
  __shared__ float t[64][65];
  int c0 = blockIdx.x * 64, r0 = blockIdx.y * 64;
  int tid = threadIdx.x;
  int rr = tid >> 4;
  int c4 = (tid & 15) * 4;
#pragma unroll
  for (int p = 0; p < 4; ++p) {
    int r = p*16 + rr;
    float4 v = *(const float4*)&w[(size_t)(r0 + r)*DM + c0 + c4];
    t[r][c4] = v.x; t[r][c4+1] = v.y; t[r][c4+2] = v.z; t[r][c4+3] = v.w;
  }
  __syncthreads();
#pragma unroll
  for (int p = 0; p < 4; ++p) {
    int c = p*16 + rr;
    us4 v;
    v[0] = f2b(t[c4+0][c]); v[1] = f2b(t[c4+1][c]);
    v[2] = f2b(t[c4+2][c]); v[3] = f2b(t[c4+3][c]);
    *(us4*)&wt[(size_t)(c0 + c)*DM + r0 + c4] = v;
  }
}

// ---------------- fused QKV GEMM: C = A(4096x2048) * WQVT^T(6144x2048) ----------------
// n section 0 -> Q bf16 [b,h,s,d] * QK_SCALE*LOG2E ; 1 -> K bf16 [b,h,s,d] ; 2 -> V^T [b,h,d,s]
__global__ __launch_bounds__(256) void gemm_qkv_kernel(const unsigned short* __restrict__ A,
                                                       const unsigned short* __restrict__ Bt,
                                                       const float* __restrict__ bq,
                                                       const float* __restrict__ bk,
                                                       const float* __restrict__ bv,
                                                       unsigned short* __restrict__ QB,
                                                       unsigned short* __restrict__ KB,
                                                       unsigned short* __restrict__ VTB) {
  __shared__ __align__(16) unsigned short As[128*32];
  __shared__ __align__(16) unsigned short Bs[128*32];
  const int K = DM;
  int n0 = blockIdx.x * 128, m0 = blockIdx.y * 128;
  int tid = threadIdx.x;
  int wid = tid >> 6, lane = tid & 63;
  int lo = lane & 15, hi = lane >> 4;
  int wm = (wid >> 1) * 64, wn = (wid & 1) * 64;

  f32x4 z = {0.f,0.f,0.f,0.f};
  f32x4 acc[4][4];
#pragma unroll
  for (int i = 0; i < 4; ++i)
#pragma unroll
    for (int j = 0; j < 4; ++j) acc[i][j] = z;

  int srow = lane >> 2;
  int sko  = (lane & 3) * 8;

  for (int kt = 0; kt < K; kt += 32) {
#pragma unroll
    for (int i = 0; i < 2; ++i) {
      int row = (wid*2 + i)*16 + srow;
      gl_lds16(&A [(size_t)(m0 + row)*K + kt + sko], &As[(wid*2 + i)*512]);
      gl_lds16(&Bt[(size_t)(n0 + row)*K + kt + sko], &Bs[(wid*2 + i)*512]);
    }
    __syncthreads();
    short8 af[4], bf[4];
#pragma unroll
    for (int f = 0; f < 4; ++f) {
      af[f] = *(const short8*)&As[(wm + f*16 + lo)*32 + hi*8];
      bf[f] = *(const short8*)&Bs[(wn + f*16 + lo)*32 + hi*8];
    }
#pragma unroll
    for (int mf = 0; mf < 4; ++mf)
#pragma unroll
      for (int nf = 0; nf < 4; ++nf)
        acc[mf][nf] = __builtin_amdgcn_mfma_f32_16x16x32_bf16(af[mf], bf[nf], acc[mf][nf], 0, 0, 0);
    __syncthreads();
  }

  int sect = n0 >> 11;   // uniform per block
  if (sect == 2) {  // V -> transposed [b,h,d,s]
#pragma unroll
    for (int mf = 0; mf < 4; ++mf) {
      int mb = m0 + wm + mf*16 + 4*hi;
      int b = mb >> 11, s = mb & 2047;
#pragma unroll
      for (int nf = 0; nf < 4; ++nf) {
        int n = n0 + wn + nf*16 + lo;
        int nl = n & 2047, h = nl >> 7, d = nl & 127;
        float bvv = bv[nl];
        us4 pk;
#pragma unroll
        for (int r = 0; r < 4; ++r) pk[r] = f2b(acc[mf][nf][r] + bvv);
        *(us4*)&VTB[(((size_t)(b*NH + h))*DK + d)*SEQ + s] = pk;
      }
    }
  } else {
    unsigned short* out = sect ? KB : QB;
    const float* bp = sect ? bk : bq;
    const float qs = sect ? 1.f : QK_SCALE * LOG2E;
#pragma unroll
    for (int mf = 0; mf < 4; ++mf)
#pragma unroll
      for (int nf = 0; nf < 4; ++nf) {
        int n = n0 + wn + nf*16 + lo;
        int nl = n & 2047, h = nl >> 7, d = nl & 127;
        float bvv = bp[nl];
#pragma unroll
        for (int r = 0; r < 4; ++r) {
          int m = m0 + wm + mf*16 + 4*hi + r;
          int b = m >> 11, s = m & 2047;
          out[(((size_t)(b*NH + h))*SEQ + s)*DK + d] = f2b((acc[mf][nf][r] + bvv) * qs);
        }
      }
  }
}

// ---------------- AO GEMM: out[m][n] = OG[m]·WOT[n] + bo, f32 out ----------------
__global__ __launch_bounds__(256) void gemm_ao_kernel(const unsigned short* __restrict__ A,
                                                      const unsigned short* __restrict__ Bt,
                                                      const float* __restrict__ bias,
                                                      float* __restrict__ out) {
  __shared__ __align__(16) unsigned short As[128*32];
  __shared__ __align__(16) unsigned short Bs[128*32];
  const int K = DM;
  int bid = blockIdx.x;
  int tm = bid >> 4, tn = bid & 15;
  int m0 = tm*128, n0 = tn*128;
  int tid = threadIdx.x;
  int wid = tid >> 6, lane = tid & 63;
  int lo = lane & 15, hi = lane >> 4;
  int wm = (wid >> 1) * 64, wn = (wid & 1) * 64;

  f32x4 z = {0.f,0.f,0.f,0.f};
  f32x4 acc[4][4];
#pragma unroll
  for (int i = 0; i < 4; ++i)
#pragma unroll
    for (int j = 0; j < 4; ++j) acc[i][j] = z;

  int srow = lane >> 2;
  int sko  = (lane & 3) * 8;

  for (int kt = 0; kt < K; kt += 32) {
#pragma unroll
    for (int i = 0; i < 2; ++i) {
      int row = (wid*2 + i)*16 + srow;
      gl_lds16(&A [(size_t)(m0 + row)*K + kt + sko], &As[(wid*2 + i)*512]);
      gl_lds16(&Bt[(size_t)(n0 + row)*K + kt + sko], &Bs[(wid*2 + i)*512]);
    }
    __syncthreads();
    short8 af[4], bf[4];
#pragma unroll
    for (int f = 0; f < 4; ++f) {
      af[f] = *(const short8*)&As[(wm + f*16 + lo)*32 + hi*8];
      bf[f] = *(const short8*)&Bs[(wn + f*16 + lo)*32 + hi*8];
    }
#pragma unroll
    for (int mf = 0; mf < 4; ++mf)
#pragma unroll
      for (int nf = 0; nf < 4; ++nf)
        acc[mf][nf] = __builtin_amdgcn_mfma_f32_16x16x32_bf16(af[mf], bf[nf], acc[mf][nf], 0, 0, 0);
    __syncthreads();
  }

#pragma unroll
  for (int mf = 0; mf < 4; ++mf)
#pragma unroll
    for (int nf = 0; nf < 4; ++nf) {
      int n = n0 + wn + nf*16 + lo;
      float bvv = bias[n];
#pragma unroll
      for (int r = 0; r < 4; ++r) {
        int m = m0 + wm + mf*16 + 4*hi + r;
        out[(size_t)m*DM + n] = acc[mf][nf][r] + bvv;
      }
    }
}

// ---------------- gate: G[row][h] = sigmoid(X[row]·wg[:,h] + bg[h]) ----------------
__global__ __launch_bounds__(256) void gate_kernel(const float* __restrict__ X,
                                                   const float* __restrict__ wg,
                                                   const float* __restrict__ bg,
                                                   float* __restrict__ G) {
  __shared__ float xr[DM];
  int row = blockIdx.x;
  int tid = threadIdx.x;
  const float4* src = (const float4*)(X + (size_t)row*DM);
#pragma unroll
  for (int i = 0; i < 2; ++i)
    ((float4*)xr)[tid + i*256] = src[tid + i*256];
  __syncthreads();
  int wid = tid >> 6, lane = tid & 63;
#pragma unroll
  for (int hh = 0; hh < 4; ++hh) {
    int h = wid*4 + hh;
    float s = 0.f;
    for (int i = lane; i < DM; i += 64)
      s += xr[i] * wg[(size_t)i*NH + h];
#pragma unroll
    for (int m = 32; m >= 1; m >>= 1) s += __shfl_xor(s, m);
    if (lane == 0) {
      float x = s + bg[h];
      G[(size_t)row*NH + h] = 1.f / (1.f + __builtin_amdgcn_exp2f(-x * LOG2E));
    }
  }
}

// ---------------- flash attention, 8 waves, QBLK=128, reg-staged K/V pipeline ----------
// Q [bh][s][d] bf16 (pre-scaled by QK_SCALE*LOG2E), K [bh][s][d] bf16, VT [bh][d][s] bf16,
// biasb [b][s][s] bf16. grid: 512 blocks (h fastest), 512 threads.
__global__ __launch_bounds__(512) void attn_kernel(const unsigned short* __restrict__ Q,
                                                   const unsigned short* __restrict__ Kb,
                                                   const unsigned short* __restrict__ VT,
                                                   const unsigned short* __restrict__ biasb,
                                                   const float* __restrict__ G,
                                                   unsigned short* __restrict__ OG) {
  __shared__ __align__(16) unsigned short kbuf[64*128];   // [key][d], XOR-swizzled 256B rows
  __shared__ __align__(16) unsigned short vbuf[128*64];   // [d][key], XOR-swizzled 128B rows
  __shared__ __align__(16) unsigned short pbuf[8*16*64];  // per-wave P bf16, swizzled 128B rows

  int bid = blockIdx.x;
  int h  = bid & 15;
  int b  = (bid >> 4) & 1;
  int qt = bid >> 5;
  int bh = b*NH + h;

  int tid = threadIdx.x, wid = tid >> 6, lane = tid & 63;
  int lo = lane & 15, hi = lane >> 4;
  int qw0 = qt*128 + wid*16;

  float hs2 = __builtin_amdgcn_exp2f(-(float)(h+1) * 0.5f) * LOG2E;

  short8 qf[4];
#pragma unroll
  for (int ks = 0; ks < 4; ++ks)
    qf[ks] = *(const short8*)&Q[((size_t)bh*SEQ + qw0 + lo)*DK + ks*32 + hi*8];

  f32x4 zero4 = {0.f,0.f,0.f,0.f};
  f32x4 acco[8];
#pragma unroll
  for (int f = 0; f < 8; ++f) acco[f] = zero4;
  float mrun[4], lrun[4];
#pragma unroll
  for (int r = 0; r < 4; ++r) { mrun[r] = -__builtin_inff(); lrun[r] = 0.f; }

  const char* kbase = (const char*)Kb + ((size_t)bh*SEQ)*DK*2;
  const char* vbase = (const char*)VT + ((size_t)bh*DK)*SEQ*2;
  const unsigned short* bb = biasb + ((size_t)b*SEQ + qw0 + 4*hi)*SEQ + lo;
  char* pb = (char*)pbuf + wid*2048;

  // per-thread staging geometry (2 chunks of 16B for K and V each)
  int krow[2], vrow[2];
  char* kdst[2]; char* vdst[2];
  int koff = (tid & 15) * 16;
  int voff = (tid & 7) * 16;
#pragma unroll
  for (int c = 0; c < 2; ++c) {
    krow[c] = c*32 + (tid >> 4);          // 0..63
    vrow[c] = c*64 + (tid >> 3);          // 0..127
    kdst[c] = (char*)kbuf + krow[c]*256 + (koff ^ ((krow[c] & 7) << 4));
    vdst[c] = (char*)vbuf + vrow[c]*128 + (voff ^ ((vrow[c] & 7) << 4));
  }
  int4 krg[2], vrg[2];

#define LOADKV(KT)                                                                       \
  _Pragma("unroll")                                                                      \
  for (int c = 0; c < 2; ++c) {                                                          \
    krg[c] = *(const int4*)(kbase + (size_t)((KT) + krow[c])*256 + koff);                \
    vrg[c] = *(const int4*)(vbase + (size_t)vrow[c]*4096 + (size_t)(KT)*2 + voff);       \
  }

  LOADKV(0);
#pragma unroll
  for (int c = 0; c < 2; ++c) { *(int4*)kdst[c] = krg[c]; *(int4*)vdst[c] = vrg[c]; }
  __syncthreads();

  for (int kt = 0; kt < SEQ; kt += 64) {
    bool more = (kt + 64) < SEQ;
    if (more) { LOADKV(kt + 64); }

    // prefetch bias for this tile (latency hides under QK^T)
    unsigned short br[4][4];
#pragma unroll
    for (int r = 0; r < 4; ++r)
#pragma unroll
      for (int nf = 0; nf < 4; ++nf)
        br[r][nf] = bb[(size_t)r*SEQ + kt + nf*16];

    // ---- QK^T: S[16q x 64k] per wave ----
    f32x4 sf[4];
#pragma unroll
    for (int nf = 0; nf < 4; ++nf) {
      f32x4 a = zero4;
#pragma unroll
      for (int ks = 0; ks < 4; ++ks) {
        int krw = nf*16 + lo;
        int cb = (ks*32 + hi*8)*2;
        short8 kf = *(const short8*)((const char*)kbuf + krw*256 + (cb ^ ((krw & 7) << 4)));
        a = __builtin_amdgcn_mfma_f32_16x16x32_bf16(qf[ks], kf, a, 0, 0, 0);
      }
      sf[nf] = a;
    }
#pragma unroll
    for (int nf = 0; nf < 4; ++nf)
#pragma unroll
      for (int r = 0; r < 4; ++r)
        sf[nf][r] = fmaf(b2f(br[r][nf]), hs2, sf[nf][r]);

    // ---- online softmax (base 2) ----
    float sc[4];
#pragma unroll
    for (int r = 0; r < 4; ++r) {
      float tm = fmaxf(fmaxf(sf[0][r], sf[1][r]), fmaxf(sf[2][r], sf[3][r]));
      tm = fmaxf(tm, __shfl_xor(tm, 1));
      tm = fmaxf(tm, __shfl_xor(tm, 2));
      tm = fmaxf(tm, __shfl_xor(tm, 4));
      tm = fmaxf(tm, __shfl_xor(tm, 8));
      float mnew = fmaxf(mrun[r], tm);
      float s = __builtin_amdgcn_exp2f(mrun[r] - mnew);
      mrun[r] = mnew; sc[r] = s;
      int prow = 4*hi + r;
      float rs = 0.f;
#pragma unroll
      for (int nf = 0; nf < 4; ++nf) {
        float p = __builtin_amdgcn_exp2f(sf[nf][r] - mnew);
        rs += p;
        *(unsigned short*)(pb + prow*128 + ((((nf*16 + lo)*2)) ^ ((prow & 7) << 4))) = f2b(p);
      }
      rs += __shfl_xor(rs, 1); rs += __shfl_xor(rs, 2);
      rs += __shfl_xor(rs, 4); rs += __shfl_xor(rs, 8);
      lrun[r] = lrun[r]*s + rs;
    }
#pragma unroll
    for (int f = 0; f < 8; ++f)
#pragma unroll
      for (int r = 0; r < 4; ++r) acco[f][r] *= sc[r];

    // ---- PV: O[16q x 128d] += P[16q x 64k] * V[64k x 128d] ----
    short8 pf[2];
#pragma unroll
    for (int ks = 0; ks < 2; ++ks)
      pf[ks] = *(const short8*)(pb + lo*128 + ((ks*64 + hi*16) ^ ((lo & 7) << 4)));
#pragma unroll
    for (int f = 0; f < 8; ++f) {
#pragma unroll
      for (int ks = 0; ks < 2; ++ks) {
        int vrw = f*16 + lo;
        int cb = (ks*32 + hi*8)*2;
        short8 vf = *(const short8*)((const char*)vbuf + vrw*128 + (cb ^ ((vrw & 7) << 4)));
        acco[f] = __builtin_amdgcn_mfma_f32_16x16x32_bf16(pf[ks], vf, acco[f], 0, 0, 0);
      }
    }

    if (more) {
      __syncthreads();   // all waves done reading tile t
#pragma unroll
      for (int c = 0; c < 2; ++c) { *(int4*)kdst[c] = krg[c]; *(int4*)vdst[c] = vrg[c]; }
      __syncthreads();   // tile t+1 visible
    }
  }

  // ---- epilogue: normalize, gate, write OG[b,s, h*128+d] bf16 ----
#pragma unroll
  for (int r = 0; r < 4; ++r) {
    int qrow = qw0 + 4*hi + r;
    float inv = 1.f / lrun[r];
    float g = G[((size_t)(b*SEQ + qrow))*NH + h];
    float sgl = inv * g;
#pragma unroll
    for (int f = 0; f < 8; ++f)
      OG[((size_t)(b*SEQ) + qrow)*DM + h*DK + f*16 + lo] = f2b(acco[f][r] * sgl);
  }
}

// ---------------- launcher ----------------
extern "C" void kernel_launch(void* const* d_in, const int* in_sizes, int n_in,
                              void* d_out, int out_size, void* d_ws, size_t ws_size,
                              hipStream_t stream) {
  const float* states    = (const float*)d_in[0];
  const float* bias_mask = (const float*)d_in[1];
  const float* wq = (const float*)d_in[2];
  const float* bq = (const float*)d_in[3];
  const float* wk = (const float*)d_in[4];
  const float* bk = (const float*)d_in[5];
  const float* wv = (const float*)d_in[6];
  const float* bv = (const float*)d_in[7];
  const float* wg = (const float*)d_in[8];
  const float* bg = (const float*)d_in[9];
  const float* wo = (const float*)d_in[10];
  const float* bo = (const float*)d_in[11];

  char* ws = (char*)d_ws;
  unsigned short* XB   = (unsigned short*)(ws + 0);              // aliased by OGB later
  unsigned short* OGB  = XB;
  unsigned short* WQVT = (unsigned short*)(ws + 16777216UL);     // 3 x 8.39MB contiguous
  unsigned short* WQT  = WQVT;
  unsigned short* WKT  = (unsigned short*)(ws + 25165824UL);
  unsigned short* WVT  = (unsigned short*)(ws + 33554432UL);
  unsigned short* WOT  = (unsigned short*)(ws + 41943040UL);
  unsigned short* QB   = (unsigned short*)(ws + 50331648UL);
  unsigned short* KB   = (unsigned short*)(ws + 67108864UL);
  unsigned short* VTB  = (unsigned short*)(ws + 83886080UL);
  unsigned short* BIASB= (unsigned short*)(ws + 100663296UL);
  float*          GB   = (float*)         (ws + 117440512UL);

  cast_bf16_kernel<<<4096, 256, 0, stream>>>(states, XB);
  cast_bf16_kernel<<<4096, 256, 0, stream>>>(bias_mask, BIASB);
  dim3 tg(32, 32);
  transpose_cast_kernel<<<tg, 256, 0, stream>>>(wq, WQT);
  transpose_cast_kernel<<<tg, 256, 0, stream>>>(wk, WKT);
  transpose_cast_kernel<<<tg, 256, 0, stream>>>(wv, WVT);
  transpose_cast_kernel<<<tg, 256, 0, stream>>>(wo, WOT);

  gemm_qkv_kernel<<<dim3(48, 32), 256, 0, stream>>>(XB, WQVT, bq, bk, bv, QB, KB, VTB);

  gate_kernel<<<4096, 256, 0, stream>>>(states, wg, bg, GB);

  attn_kernel<<<512, 512, 0, stream>>>(QB, KB, VTB, BIASB, GB, OGB);

  gemm_ao_kernel<<<512, 256, 0, stream>>>(OGB, WOT, bo, (float*)d_out);
}